// Round 4
// baseline (334.257 us; speedup 1.0000x reference)
//
#include <hip/hip_runtime.h>
#include <stdint.h>

// B=32, C=256, P=2 pods, 64x64 spatial (pos=4096). f32 I/O, bf16 MFMA inside.
// R8 (resubmit — R3 bench was an infra container failure, kernel never ran):
//  k_fwd: repack slot = wave^(quad<<1) breaks the 8-way LDS bank conflict
//    (was smem[pos*8+wave]: quad*4096==0 mod 128 -> 8 lanes/bank, 64 scalar
//    writes/thread ~1077 cyc/wave). New pattern: dword%32 = 4*(l15%8) +
//    ((wave>>1)^quad) -> 2-way = free. Drain un-permutes with a wave-uniform
//    STATIC u32 permute (qp=(2i+wave/4)&3) -> F global bytes bit-identical.
//  k_gemm: 48 KiB (A single 16K + B dbuf 2x16K) -> 3 blocks/CU (was 64K/2).
//    Early issueB (global_load_lds dwordx4, linear dest, R6-proven 0-conflict),
//    conflict-free linear writeA (R7-proven), 2 barriers/ks.
//  k_inv: byte-identical to R5.
// d_out slot map (16 KiB per img): lo 8 KiB = f6, hi 8 KiB = F via Faddr().

typedef __attribute__((ext_vector_type(4))) float f32x4_t;
typedef __attribute__((ext_vector_type(8))) __bf16 bf16x8_t;
typedef __attribute__((ext_vector_type(8))) unsigned short u16x8_t;
typedef __attribute__((ext_vector_type(4))) unsigned short u16x4_t;
typedef __attribute__((ext_vector_type(4))) unsigned int u32x4_t;

__device__ __forceinline__ float bf2f(unsigned short u) {
  union { unsigned int i; float f; } x; x.i = ((unsigned int)u) << 16; return x.f;
}
__device__ __forceinline__ unsigned short f2bf(float f) {   // RNE
  union { float f; unsigned int i; } x; x.f = f;
  unsigned int i = x.i;
  return (unsigned short)((i + 0x7FFFu + ((i >> 16) & 1u)) >> 16);
}
__device__ __forceinline__ unsigned short f2bf_t(float f) { // truncate (staging)
  union { float f; unsigned int i; } x; x.f = f;
  return (unsigned short)(x.i >> 16);
}
// linear u16 index into F -> physical u16 offset in d_out (slot upper halves)
__device__ __forceinline__ size_t Faddr(size_t f) {
  return ((f >> 12) << 13) + 4096 + (f & 4095);
}

// ---------------- k_fwd: 2D WHT via MFMA, write F tiled ----------------
// block = 512 thr = 8 waves, wave -> image c = cg*8+wave; grid (32 cg, 32 b)
__global__ __launch_bounds__(512) void k_fwd(const float* __restrict__ x,
                                             unsigned short* __restrict__ obuf) {
  __shared__ unsigned short smem[36864];       // 72 KiB: 8x T1t(4608) / Fbuf overlay
  int tid = threadIdx.x;
  int lane = tid & 63, wave = tid >> 6;
  int quad = lane >> 4, l15 = lane & 15;
  int cg = blockIdx.x, b = blockIdx.y;
  size_t img = (size_t)b * 256 + cg * 8 + wave;
  unsigned short* T1t = smem + wave * 4608;    // per-wave [64][72] u16 tile

  // stage X coalesced: flat float4 -> bf16 tile [h][w] (stride 72)
  const float* xim = x + img * 4096;
#pragma unroll
  for (int l = 0; l < 16; l++) {
    int e = (l * 64 + lane) * 4;
    f32x4_t sv = *(const f32x4_t*)(xim + e);
    u16x4_t u;
#pragma unroll
    for (int j = 0; j < 4; j++) u[j] = f2bf_t(sv[j]);
    int row = e >> 6, col = e & 63;
    *(u16x4_t*)&T1t[row * 72 + col] = u;
  }

  // H fragments: hf[kc][t][j] = sign(parity((kc*32+quad*8+j) & (t*16+l15)))
  bf16x8_t hf[2][4];
#pragma unroll
  for (int kc = 0; kc < 2; kc++)
#pragma unroll
    for (int t = 0; t < 4; t++) {
      bf16x8_t h;
#pragma unroll
      for (int j = 0; j < 8; j++) {
        int k = kc * 32 + quad * 8 + j, n = t * 16 + l15;
        h[j] = (__builtin_popcount(k & n) & 1) ? (__bf16)-1.0f : (__bf16)1.0f;
      }
      hf[kc][t] = h;
    }

  // X A-fragments from LDS (b128, same-wave ordering after staging writes)
  bf16x8_t xa[4][2];
#pragma unroll
  for (int mt = 0; mt < 4; mt++)
#pragma unroll
    for (int kc = 0; kc < 2; kc++)
      xa[mt][kc] = *(const bf16x8_t*)&T1t[(mt * 16 + l15) * 72 + kc * 32 + quad * 8];

  // GEMM1: T1 = X*H, strip-mined by nt; store transposed [kw][h] into T1t
#pragma unroll
  for (int nt = 0; nt < 4; nt++) {
    f32x4_t a1c[4];
#pragma unroll
    for (int mt = 0; mt < 4; mt++) a1c[mt] = (f32x4_t){0.f, 0.f, 0.f, 0.f};
#pragma unroll
    for (int kc = 0; kc < 2; kc++)
#pragma unroll
      for (int mt = 0; mt < 4; mt++)
        a1c[mt] = __builtin_amdgcn_mfma_f32_16x16x32_bf16(xa[mt][kc], hf[kc][nt], a1c[mt], 0, 0, 0);
#pragma unroll
    for (int mt = 0; mt < 4; mt++) {
      u16x4_t t4;
#pragma unroll
      for (int r = 0; r < 4; r++) t4[r] = f2bf_t(a1c[mt][r]);
      *(u16x4_t*)&T1t[(nt * 16 + l15) * 72 + mt * 16 + quad * 4] = t4;
    }
  }

  // GEMM2: f2 = H*T1
  f32x4_t acc[4][4];
#pragma unroll
  for (int mt = 0; mt < 4; mt++)
#pragma unroll
    for (int nt = 0; nt < 4; nt++) acc[mt][nt] = (f32x4_t){0.f, 0.f, 0.f, 0.f};
#pragma unroll
  for (int kc = 0; kc < 2; kc++)
#pragma unroll
    for (int nt = 0; nt < 4; nt++) {
      bf16x8_t bfr = *(bf16x8_t*)&T1t[(nt * 16 + l15) * 72 + kc * 32 + quad * 8];
#pragma unroll
      for (int mt = 0; mt < 4; mt++)
        acc[mt][nt] = __builtin_amdgcn_mfma_f32_16x16x32_bf16(hf[kc][mt], bfr, acc[mt][nt], 0, 0, 0);
    }

  __syncthreads();                             // all T1t reads done before overlay
  // fill Fbuf[pos][slot]: slot = wave ^ (quad<<1); note (pos>>8)&3 == quad,
  // so the in-chunk permutation is a pure function of pos (undone in drain).
  // Banks: dword%32 = 4*(l15%8) + ((wave>>1)^quad) -> 2 lanes/bank = free.
#pragma unroll
  for (int mt = 0; mt < 4; mt++)
#pragma unroll
    for (int nt = 0; nt < 4; nt++)
#pragma unroll
      for (int r = 0; r < 4; r++) {
        int pos = (mt * 16 + quad * 4 + r) * 64 + nt * 16 + l15;  // kh*64+kw
        smem[pos * 8 + (wave ^ (quad << 1))] = f2bf(acc[mt][nt][r]);
      }
  __syncthreads();
  // drain: coalesced; un-permute u32s by qp=(pos>>8)&3 = (2i + wave/4)&3
  // (wave-uniform, static per unrolled i) -> F global bytes == R5 layout.
  size_t fbase = ((size_t)b * 32 + cg) * 4096;
  int hb = wave >> 2;                          // 0 or 1
  if (hb) {
#pragma unroll
    for (int i = 0; i < 8; i++) {
      int pos = i * 512 + tid;
      u32x4_t c = *(u32x4_t*)&smem[pos * 8];
      const int q = (2 * i + 1) & 3;
      u32x4_t o;
      o[0] = c[0 ^ q]; o[1] = c[1 ^ q]; o[2] = c[2 ^ q]; o[3] = c[3 ^ q];
      *(u32x4_t*)(obuf + Faddr((fbase + pos) * 8)) = o;
    }
  } else {
#pragma unroll
    for (int i = 0; i < 8; i++) {
      int pos = i * 512 + tid;
      u32x4_t c = *(u32x4_t*)&smem[pos * 8];
      const int q = (2 * i) & 3;
      u32x4_t o;
      o[0] = c[0 ^ q]; o[1] = c[1 ^ q]; o[2] = c[2 ^ q]; o[3] = c[3 ^ q];
      *(u32x4_t*)(obuf + Faddr((fbase + pos) * 8)) = o;
    }
  }
}

// ---------------- k_gemm: Wcat @ F + soft-threshold (R8: 48 KiB, 3 blk/CU) ----------------
// block = 256 thr = 4 waves; grid (32 n-tile, 4 m-tile, 32 b)
// LDS 48 KiB: A single [128 m][8 slot] (slot s holds gch=s^(m&7)) @0;
// B dbuf 2x[8 cch][128 r] linear (global_load_lds dest) @8192.
// Per ks: issueB(next)+fetchA(next) -> MFMA(cur) -> bar -> writeA -> bar.
__global__ __launch_bounds__(256) void k_gemm(const float* __restrict__ Wf,
                                              const float* __restrict__ vv,
                                              const float* __restrict__ TT,
                                              unsigned short* __restrict__ obuf) {
  __shared__ unsigned short smem2[24576];      // 48 KiB; epilogue overlays [0..8704)
  unsigned short* Alds = smem2;
  int tid = threadIdx.x;
  int lane = tid & 63, wave = tid >> 6;
  int quad = lane >> 4, l15 = lane & 15;
  int wm = wave & 1, wn = wave >> 1;
  int n0 = blockIdx.x * 128;                   // pos tile
  int m0 = blockIdx.y * 128;                   // Wcat row tile (m=2o+p)
  int b  = blockIdx.z;

  f32x4_t acc[4][4];
#pragma unroll
  for (int mt = 0; mt < 4; mt++)
#pragma unroll
    for (int nt = 0; nt < 4; nt++) acc[mt][nt] = (f32x4_t){0.f, 0.f, 0.f, 0.f};

  // ---- staging helpers ----
  auto issueB = [&](int ks, int buf) {         // 4x global_load_lds dwordx4, linear dest
    unsigned short* Bl = smem2 + 8192 + buf * 8192;
#pragma unroll
    for (int i = 0; i < 4; i++) {
      int idx = i * 256 + tid;
      int r = idx & 127, cch = idx >> 7;
      size_t f = (((size_t)b * 32 + ks * 8 + cch) * 4096 + n0 + r) * 8;
      const unsigned short* src = obuf + Faddr(f);
      __builtin_amdgcn_global_load_lds(
          (const __attribute__((address_space(1))) void*)src,
          (__attribute__((address_space(3))) void*)(Bl + idx * 8), 16, 0, 0);
    }
  };
  auto fetchA = [&](int ks, f32x4_t (&ar)[4][2]) {  // gch-swizzled coalesced fetch
    int k0 = ks * 64;
#pragma unroll
    for (int i = 0; i < 4; i++) {
      int idx = i * 256 + tid;
      int r = idx >> 3, cch = idx & 7;
      int gch = cch ^ (r & 7);
      int m = m0 + r;
      const float* wp = Wf + ((m & 1) << 16) + ((m >> 1) << 8) + k0 + gch * 8;
      ar[i][0] = *(const f32x4_t*)wp;
      ar[i][1] = *(const f32x4_t*)(wp + 4);
    }
  };
  auto writeA = [&](f32x4_t (&ar)[4][2]) {     // convert + LINEAR store (0-conflict)
#pragma unroll
    for (int i = 0; i < 4; i++) {
      int idx = i * 256 + tid;
      u16x8_t u;
#pragma unroll
      for (int j = 0; j < 4; j++) { u[j] = f2bf_t(ar[i][0][j]); u[4 + j] = f2bf_t(ar[i][1][j]); }
      *(u16x8_t*)&Alds[idx * 8] = u;           // slot cch of row r holds gch=cch^(r&7)
    }
  };

  f32x4_t areg[4][2];
  issueB(0, 0);                                // B(0) DMA in flight during A(0) stage
  fetchA(0, areg);
  writeA(areg);
  __syncthreads();                             // drains vmcnt: B(0)+A(0) ready

  for (int ks = 0; ks < 4; ++ks) {
    int p = ks & 1;
    if (ks < 3) {                              // prefetch next tile before compute
      issueB(ks + 1, p ^ 1);
      fetchA(ks + 1, areg);
    }
    unsigned short* Bl = smem2 + 8192 + p * 8192;
#pragma unroll
    for (int kk = 0; kk < 2; ++kk) {
      bf16x8_t af[4], bfr[4];
#pragma unroll
      for (int mt = 0; mt < 4; mt++) {
        int row = wm * 64 + mt * 16 + l15;
        int s = (kk * 4 + quad) ^ (row & 7);   // swizzled A read (conflict-free, R5)
        af[mt] = *(const bf16x8_t*)&Alds[row * 64 + s * 8];
      }
      int ch = kk * 4 + quad;
#pragma unroll
      for (int nt = 0; nt < 4; nt++)           // linear B read (conflict-free per R6 PMC)
        bfr[nt] = *(const bf16x8_t*)&Bl[ch * 1024 + (wn * 64 + nt * 16 + l15) * 8];
#pragma unroll
      for (int mt = 0; mt < 4; mt++)
#pragma unroll
        for (int nt = 0; nt < 4; nt++)
          acc[mt][nt] = __builtin_amdgcn_mfma_f32_16x16x32_bf16(af[mt], bfr[nt], acc[mt][nt], 0, 0, 0);
    }
    __syncthreads();                           // Alds+B[p] reads done; B(ks+1) landed
    if (ks < 3) {
      writeA(areg);                            // A(ks+1) into the (single) A buffer
      __syncthreads();                         // publish A(ks+1)
    }
  }

  // epilogue: v-scale + soft-threshold both pods (reg parity = pod)
  // -> LDS tile [64 o][136 pos-stride] -> coalesced f6 row stores (slot-lo)
#pragma unroll
  for (int nt = 0; nt < 4; nt++) {
    int posl = wn * 64 + nt * 16 + l15;
    int pos = n0 + posl;
    float v0 = vv[pos], v1 = vv[4096 + pos];
    float t0 = TT[pos], t1 = TT[4096 + pos];
#pragma unroll
    for (int mt = 0; mt < 4; mt++)
#pragma unroll
      for (int rp = 0; rp < 2; rp++) {
        int ol = wm * 32 + mt * 8 + quad * 2 + rp;
        float z0 = acc[mt][nt][rp * 2 + 0] * v0;
        float z1 = acc[mt][nt][rp * 2 + 1] * v1;
        float s0 = copysignf(fmaxf(fabsf(z0) - t0, 0.f), z0);
        float s1 = copysignf(fmaxf(fabsf(z1) - t1, 0.f), z1);
        smem2[ol * 136 + posl] = f2bf(s0 + s1);
      }
  }
  __syncthreads();
  int o0 = m0 >> 1;
#pragma unroll
  for (int i = 0; i < 4; i++) {
    int ci = i * 256 + tid;                    // 1024 chunks = 64 rows x 16
    int row = ci >> 4, cc = ci & 15;
    u16x8_t vch = *(u16x8_t*)&smem2[row * 136 + cc * 8];
    size_t img = (size_t)b * 256 + o0 + row;
    *(u16x8_t*)(obuf + img * 8192 + n0 + cc * 8) = vch;
  }
}

// ---------------- k_inv: inverse 2D WHT via MFMA + /4096 + x (unchanged R5) ----------------
// block = 256 thr = 4 waves, wave -> image; grid 2048
__global__ __launch_bounds__(256) void k_inv(const float* __restrict__ x,
                                             unsigned short* __restrict__ obuf) {
  __shared__ unsigned short smem[18432];       // 4x per-wave [64][72] u16 tile
  int tid = threadIdx.x;
  int lane = tid & 63, wave = tid >> 6;
  int quad = lane >> 4, l15 = lane & 15;
  size_t img = (size_t)blockIdx.x * 4 + wave;
  unsigned short* T1t = smem + wave * 4608;

  // stage f6 coalesced (slot-lo u16x8) -> LDS tile [h][w] stride 72
#pragma unroll
  for (int l = 0; l < 8; l++) {
    int e = (l * 64 + lane) * 8;
    u16x8_t sv = *(const u16x8_t*)(obuf + img * 8192 + e);
    int row = e >> 6, col = e & 63;
    *(u16x8_t*)&T1t[row * 72 + col] = sv;
  }

  bf16x8_t hf[2][4];
#pragma unroll
  for (int kc = 0; kc < 2; kc++)
#pragma unroll
    for (int t = 0; t < 4; t++) {
      bf16x8_t h;
#pragma unroll
      for (int j = 0; j < 8; j++) {
        int k = kc * 32 + quad * 8 + j, n = t * 16 + l15;
        h[j] = (__builtin_popcount(k & n) & 1) ? (__bf16)-1.0f : (__bf16)1.0f;
      }
      hf[kc][t] = h;
    }

  // A-frags from LDS
  bf16x8_t fa[4][2];
#pragma unroll
  for (int mt = 0; mt < 4; mt++)
#pragma unroll
    for (int kc = 0; kc < 2; kc++)
      fa[mt][kc] = *(const bf16x8_t*)&T1t[(mt * 16 + l15) * 72 + kc * 32 + quad * 8];

  // GEMM1: U = f6*H, strip-mined; store transposed into T1t (reuse)
#pragma unroll
  for (int nt = 0; nt < 4; nt++) {
    f32x4_t a1c[4];
#pragma unroll
    for (int mt = 0; mt < 4; mt++) a1c[mt] = (f32x4_t){0.f, 0.f, 0.f, 0.f};
#pragma unroll
    for (int kc = 0; kc < 2; kc++)
#pragma unroll
      for (int mt = 0; mt < 4; mt++)
        a1c[mt] = __builtin_amdgcn_mfma_f32_16x16x32_bf16(fa[mt][kc], hf[kc][nt], a1c[mt], 0, 0, 0);
#pragma unroll
    for (int mt = 0; mt < 4; mt++) {
      u16x4_t t4;
#pragma unroll
      for (int r = 0; r < 4; r++) t4[r] = f2bf_t(a1c[mt][r]);
      *(u16x4_t*)&T1t[(nt * 16 + l15) * 72 + mt * 16 + quad * 4] = t4;
    }
  }

  // GEMM2: V = H*U
  f32x4_t acc[4][4];
#pragma unroll
  for (int mt = 0; mt < 4; mt++)
#pragma unroll
    for (int nt = 0; nt < 4; nt++) acc[mt][nt] = (f32x4_t){0.f, 0.f, 0.f, 0.f};
#pragma unroll
  for (int kc = 0; kc < 2; kc++)
#pragma unroll
    for (int nt = 0; nt < 4; nt++) {
      bf16x8_t bfr = *(bf16x8_t*)&T1t[(nt * 16 + l15) * 72 + kc * 32 + quad * 8];
#pragma unroll
      for (int mt = 0; mt < 4; mt++)
        acc[mt][nt] = __builtin_amdgcn_mfma_f32_16x16x32_bf16(hf[kc][mt], bfr, acc[mt][nt], 0, 0, 0);
    }

  // acc -> LDS tile [hh][ww] as bf16*(1/4096) (scalar u16 writes, 2-way free)
  const float sc = 1.0f / 4096.0f;
#pragma unroll
  for (int mt = 0; mt < 4; mt++)
#pragma unroll
    for (int nt = 0; nt < 4; nt++)
#pragma unroll
      for (int r = 0; r < 4; r++)
        T1t[(mt * 16 + quad * 4 + r) * 72 + nt * 16 + l15] = f2bf(acc[mt][nt][r] * sc);

  // drain: coalesced — LDS row chunks + x residual -> f32 out (in-place slot)
  float* outf = (float*)obuf;
  const float* xim = x + img * 4096;
#pragma unroll
  for (int l = 0; l < 8; l++) {
    int e = (l * 64 + lane) * 8;
    int row = e >> 6, col = e & 63;
    u16x8_t tv = *(u16x8_t*)&T1t[row * 72 + col];
    f32x4_t x0 = *(const f32x4_t*)(xim + e);
    f32x4_t x1 = *(const f32x4_t*)(xim + e + 4);
    f32x4_t o0, o1;
#pragma unroll
    for (int j = 0; j < 4; j++) { o0[j] = bf2f(tv[j]) + x0[j]; o1[j] = bf2f(tv[4 + j]) + x1[j]; }
    *(f32x4_t*)(outf + img * 4096 + e) = o0;
    *(f32x4_t*)(outf + img * 4096 + e + 4) = o1;
  }
}

extern "C" void kernel_launch(void* const* d_in, const int* in_sizes, int n_in,
                              void* d_out, int out_size, void* d_ws, size_t ws_size,
                              hipStream_t stream) {
  const float* x = (const float*)d_in[0];      // (32,256,64,64) f32
  const float* v = (const float*)d_in[1];      // (2,64,64) f32
  const float* W = (const float*)d_in[2];      // (2,256,256) f32
  const float* T = (const float*)d_in[3];      // (2,64,64) f32
  unsigned short* obuf = (unsigned short*)d_out;
  (void)d_ws; (void)ws_size; (void)in_sizes; (void)n_in; (void)out_size;

  k_fwd<<<dim3(32, 32), 512, 0, stream>>>(x, obuf);
  k_gemm<<<dim3(32, 4, 32), 256, 0, stream>>>(W, v, T, obuf);
  k_inv<<<2048, 256, 0, stream>>>(x, obuf);
}